// Round 18
// baseline (595.255 us; speedup 1.0000x reference)
//
#include <hip/hip_runtime.h>
#include <hip/hip_bf16.h>
#include <math.h>

// ---------------------------------------------------------------------------
// Gemma audio layer, round 17: attention T14 async-STAGE split.
// k_ctx and V^T are loaded to REGISTERS early (k issued before bd MFMA, V
// issued right after k's LDS write) and written to LDS late:
//   qa loads | relk gload_lds | kreg global_loads   (order pinned)
//   vmcnt(8) (drains qa+relk, kreg stays in flight) ; s_barrier ; bd MFMA
//   __syncthreads (kv_s free) ; ds_write kreg ; issue vreg loads
//   lgkmcnt(0) ; s_barrier  (vreg stays in flight) ; ac MFMA ; softmax
//   __syncthreads ; ds_write vreg ; lgkmcnt(0) ; s_barrier ; PV ; out
// LDS layouts and all math byte-identical to round 16.
// GEMMs (dual + post + relk), conv unchanged from round 16 (541 us, PASS).
// ---------------------------------------------------------------------------

#define NH_    12
#define HD_    128
#define H_     1536
#define B_     4
#define S_     4096
#define CHUNK_ 128
#define CTX_   255
#define NB_CH  32
#define QKW_   3072
#define BSTR_  4352        // 128 halo + 4096 tokens + 128 tail = 17*256

typedef unsigned short u16;
typedef short bf16x8 __attribute__((ext_vector_type(8)));
typedef float f32x4 __attribute__((ext_vector_type(4)));

static constexpr float Q_SCALE_F = (float)(0.08838834764831845 / 0.6931471805599453);
static constexpr float K_SCALE_F = (float)(1.3132616875182228 / 0.6931471805599453);

__device__ __forceinline__ u16 f2bf(float f) {
    __hip_bfloat16 h = __float2bfloat16(f);
    return __builtin_bit_cast(u16, h);
}
__device__ __forceinline__ float bf2f(u16 u) {
    unsigned int t = ((unsigned int)u) << 16;
    return __builtin_bit_cast(float, t);
}
__device__ __forceinline__ float fast_tanh(float t) {
    float u = __expf(-2.f * fabsf(t));
    float r = (1.f - u) / (1.f + u);
    return (t < 0.f) ? -r : r;
}

__device__ __forceinline__ void gload_lds16(const u16* src_global, u16* dst_lds) {
    __builtin_amdgcn_global_load_lds(
        (const __attribute__((address_space(1))) unsigned int*)src_global,
        (__attribute__((address_space(3))) unsigned int*)dst_lds,
        16, 0, 0);
}

// ---------------------------------------------------------------------------
// fp32 -> bf16 conversions (weights/pos; hs with per-batch halo layout).
// ---------------------------------------------------------------------------
__global__ __launch_bounds__(256)
void conv_bf16(const float* __restrict__ src, long long base,
               u16* __restrict__ dst, long long n,
               long long zero_below, long long zero_from,
               int mode, const float* __restrict__ pds, int ncols)
{
    long long i = ((long long)blockIdx.x * 256 + threadIdx.x) * 4;
    if (i >= n) return;
    float4 v = make_float4(0.f, 0.f, 0.f, 0.f);
    if (i >= zero_below && i < zero_from)
        v = *(const float4*)(src + base + i);
    float s = 1.f;
    if (mode == 1) {
        int row = (int)(i / ncols);
        float x = pds[row & 127];
        float sp = (x > 20.f) ? x : log1pf(__expf(x));
        s = Q_SCALE_F * sp;
    } else if (mode == 2) {
        s = K_SCALE_F;
    }
    ushort4 o = make_ushort4(f2bf(v.x * s), f2bf(v.y * s), f2bf(v.z * s), f2bf(v.w * s));
    *(ushort4*)(dst + i) = o;
}

__global__ __launch_bounds__(256)
void conv_hs(const float* __restrict__ src, long long src_row0,
             u16* __restrict__ dst, long long nelem)
{
    long long i = ((long long)blockIdx.x * 256 + threadIdx.x) * 4;
    if (i >= nelem) return;
    const int row = (int)(i / H_);
    const int col = (int)(i - (long long)row * H_);
    const int b = row / BSTR_;
    const int local = row - b * BSTR_;
    float4 v = make_float4(0.f, 0.f, 0.f, 0.f);
    if (local >= 128 && local < 128 + S_) {
        const long long srow = src_row0 + (long long)b * S_ + local - 128;
        v = *(const float4*)(src + srow * H_ + col);
    }
    ushort4 o = make_ushort4(f2bf(v.x), f2bf(v.y), f2bf(v.z), f2bf(v.w));
    *(ushort4*)(dst + i) = o;
}

// ---------------------------------------------------------------------------
// 128^2 GEMM (round-8 proven) -- kept for the small relk projection only.
// ---------------------------------------------------------------------------
#define STAGE(kt, bufc) do {                                                   \
    const int _ko = (kt) << 5;                                                 \
    gload_lds16(srcA[0] + _ko, lds + (bufc) * 4096 + pbase[0]);                \
    gload_lds16(srcA[1] + _ko, lds + (bufc) * 4096 + pbase[1]);                \
    gload_lds16(srcB[0] + _ko, lds + 16384 + (bufc) * 4096 + pbase[0]);        \
    gload_lds16(srcB[1] + _ko, lds + 16384 + (bufc) * 4096 + pbase[1]);        \
} while (0)

#define READF(afX, bfX, b) do {                                                \
    _Pragma("unroll")                                                          \
    for (int m = 0; m < 4; ++m)                                                \
        afX[m] = *(const bf16x8*)&lds[(b) * 4096 + (wr + m * 16 + lr) * 32 + sw8]; \
    _Pragma("unroll")                                                          \
    for (int n = 0; n < 4; ++n)                                                \
        bfX[n] = *(const bf16x8*)&lds[16384 + (b) * 4096 + (wc + n * 16 + lr) * 32 + sw8]; \
} while (0)

#define MFMA16(afX, bfX) do {                                                  \
    __builtin_amdgcn_s_setprio(1);                                             \
    _Pragma("unroll")                                                          \
    for (int m = 0; m < 4; ++m)                                                \
        _Pragma("unroll")                                                      \
        for (int n = 0; n < 4; ++n)                                            \
            acc[m][n] = __builtin_amdgcn_mfma_f32_16x16x32_bf16(afX[m], bfX[n], acc[m][n], 0, 0, 0); \
    __builtin_amdgcn_s_setprio(0);                                             \
} while (0)

#define ITER(t, b, afC, bfC, afN, bfN) do {                                    \
    if ((t) + 2 < nk) {                                                        \
        STAGE((t) + 2, ((b) + 2) & 3);                                         \
        asm volatile("s_waitcnt vmcnt(4)" ::: "memory");                       \
    } else {                                                                   \
        asm volatile("s_waitcnt vmcnt(0)" ::: "memory");                       \
    }                                                                          \
    __builtin_amdgcn_s_barrier();                                              \
    if ((t) + 1 < nk) READF(afN, bfN, ((b) + 1) & 3);                          \
    MFMA16(afC, bfC);                                                          \
} while (0)

__global__ __launch_bounds__(256)
void gemm_bt(const u16* __restrict__ A, const u16* __restrict__ B,
             u16* __restrict__ Cp, int M, int N, int K, int ldc)
{
    __shared__ __align__(16) u16 lds[32768];

    const int tid = threadIdx.x;
    const int w = tid >> 6, l = tid & 63;
    const int lr = l & 15, lg = l >> 4;
    const int bm = blockIdx.y * 128, bn = blockIdx.x * 128;
    const int wr = (w >> 1) * 64, wc = (w & 1) * 64;
    const int sw8 = (lg ^ ((lr >> 1) & 3)) * 8;

    const u16* srcA[2];
    const u16* srcB[2];
    int pbase[2];
#pragma unroll
    for (int c = 0; c < 2; ++c) {
        const int p = (w * 2 + c) * 64 + l;
        const int row = p >> 2;
        const int s_log = (p & 3) ^ ((row >> 1) & 3);
        pbase[c] = p * 8;
        srcA[c] = A + (size_t)(bm + row) * K + s_log * 8;
        srcB[c] = B + (size_t)(bn + row) * K + s_log * 8;
    }

    f32x4 acc[4][4];
#pragma unroll
    for (int m = 0; m < 4; ++m)
#pragma unroll
        for (int n = 0; n < 4; ++n) acc[m][n] = (f32x4){0.f, 0.f, 0.f, 0.f};

    const int nk = K >> 5;
    bf16x8 af0[4], bf0[4], af1[4], bf1[4];

    STAGE(0, 0);
    STAGE(1, 1);
    asm volatile("s_waitcnt vmcnt(4)" ::: "memory");
    __builtin_amdgcn_s_barrier();
    READF(af0, bf0, 0);

    for (int t0 = 0; t0 < nk; t0 += 4) {
        ITER(t0 + 0, 0, af0, bf0, af1, bf1);
        ITER(t0 + 1, 1, af1, bf1, af0, bf0);
        ITER(t0 + 2, 2, af0, bf0, af1, bf1);
        ITER(t0 + 3, 3, af1, bf1, af0, bf0);
    }

#pragma unroll
    for (int h = 0; h < 2; ++h) {
        if (wr == h * 64) {
#pragma unroll
            for (int m = 0; m < 4; ++m)
#pragma unroll
                for (int n = 0; n < 4; ++n)
#pragma unroll
                    for (int r = 0; r < 4; ++r)
                        lds[(m * 16 + lg * 4 + r) * 136 + wc + n * 16 + lr] =
                            f2bf(acc[m][n][r]);
        }
        __syncthreads();
#pragma unroll
        for (int it = 0; it < 4; ++it) {
            const int sid = it * 256 + tid;
            const int row = sid >> 4, sl = sid & 15;
            int4 val = *(const int4*)&lds[row * 136 + sl * 8];
            *(int4*)(Cp + (size_t)(bm + h * 64 + row) * ldc + bn + sl * 8) = val;
        }
        __syncthreads();
    }
}

// ---------------------------------------------------------------------------
// 256x256xBK32 GEMM body (round-16 proven: ring-4, STAGE-3-AHEAD,
// vmcnt 12/8/4/0, read(t) after barrier(t)).
// ---------------------------------------------------------------------------
#define STG2(kt, bufc) do {                                                    \
    const int _ko = (kt) << 5;                                                 \
    gload_lds16(srcA[0] + _ko, lds + (bufc) * 16384 + pbase[0]);               \
    gload_lds16(srcA[1] + _ko, lds + (bufc) * 16384 + pbase[1]);               \
    gload_lds16(srcB[0] + _ko, lds + (bufc) * 16384 + 8192 + pbase[0]);        \
    gload_lds16(srcB[1] + _ko, lds + (bufc) * 16384 + 8192 + pbase[1]);        \
} while (0)

#define IT3(t, b) do {                                                         \
    if ((t) + 3 < nk) {                                                        \
        STG2((t) + 3, ((b) + 3) & 3);                                          \
        asm volatile("s_waitcnt vmcnt(12)" ::: "memory");                      \
    } else if ((t) + 3 == nk) {                                                \
        asm volatile("s_waitcnt vmcnt(8)" ::: "memory");                       \
    } else if ((t) + 2 == nk) {                                                \
        asm volatile("s_waitcnt vmcnt(4)" ::: "memory");                       \
    } else {                                                                   \
        asm volatile("s_waitcnt vmcnt(0)" ::: "memory");                       \
    }                                                                          \
    __builtin_amdgcn_s_barrier();                                              \
    bf16x8 af[8], bfr[4];                                                      \
    _Pragma("unroll")                                                          \
    for (int m = 0; m < 8; ++m)                                                \
        af[m] = *(const bf16x8*)&lds[(b) * 16384 + (mbase + m * 16 + lr) * 32 + sw8]; \
    _Pragma("unroll")                                                          \
    for (int n = 0; n < 4; ++n)                                                \
        bfr[n] = *(const bf16x8*)&lds[(b) * 16384 + 8192 + (nbase + n * 16 + lr) * 32 + sw8]; \
    __builtin_amdgcn_s_setprio(1);                                             \
    _Pragma("unroll")                                                          \
    for (int m = 0; m < 8; ++m)                                                \
        _Pragma("unroll")                                                      \
        for (int n = 0; n < 4; ++n)                                            \
            acc[m][n] = __builtin_amdgcn_mfma_f32_16x16x32_bf16(af[m], bfr[n], acc[m][n], 0, 0, 0); \
    __builtin_amdgcn_s_setprio(0);                                             \
} while (0)

template<int OUTB>
__device__ __forceinline__
void gemm256_body(const u16* __restrict__ A, const u16* __restrict__ B,
                  void* __restrict__ Cp, int N, int K, int ldc,
                  int bx, int by, u16* lds)
{
    (void)N;
    const int tid = threadIdx.x;               // 0..511
    const int w = tid >> 6, l = tid & 63;
    const int lr = l & 15, lg = l >> 4;
    const int wrow = w >> 2, wcol = w & 3;     // 2 x 4 wave grid
    const int bm = by * 256, bn = bx * 256;
    const int mbase = wrow * 128;
    const int nbase = wcol * 64;
    const int sw8 = (lg ^ ((lr >> 1) & 3)) * 8;

    const u16* srcA[2];
    const u16* srcB[2];
    int pbase[2];
#pragma unroll
    for (int c = 0; c < 2; ++c) {
        const int p = c * 512 + tid;
        const int row = p >> 2;
        const int s_log = (p & 3) ^ ((row >> 1) & 3);
        pbase[c] = p * 8;
        srcA[c] = A + (size_t)(bm + row) * K + s_log * 8;
        srcB[c] = B + (size_t)(bn + row) * K + s_log * 8;
    }

    f32x4 acc[8][4];
#pragma unroll
    for (int m = 0; m < 8; ++m)
#pragma unroll
        for (int n = 0; n < 4; ++n) acc[m][n] = (f32x4){0.f, 0.f, 0.f, 0.f};

    const int nk = K >> 5;                     // 48 for K=1536; nk % 4 == 0
    STG2(0, 0);
    STG2(1, 1);
    STG2(2, 2);
    for (int t0 = 0; t0 < nk; t0 += 4) {
        IT3(t0 + 0, 0);
        IT3(t0 + 1, 1);
        IT3(t0 + 2, 2);
        IT3(t0 + 3, 3);
    }

    __syncthreads();

    if (OUTB) {
#pragma unroll
        for (int h = 0; h < 2; ++h) {
            if (wrow == h) {
#pragma unroll
                for (int m = 0; m < 8; ++m)
#pragma unroll
                    for (int n = 0; n < 4; ++n)
#pragma unroll
                        for (int r = 0; r < 4; ++r)
                            lds[(m * 16 + lg * 4 + r) * 264 + nbase + n * 16 + lr] =
                                f2bf(acc[m][n][r]);
            }
            __syncthreads();
#pragma unroll
            for (int it = 0; it < 8; ++it) {
                const int sid = it * 512 + tid;
                const int row = sid >> 5, sl = sid & 31;
                int4 val = *(const int4*)&lds[row * 264 + sl * 8];
                *(int4*)((u16*)Cp + (size_t)(bm + h * 128 + row) * ldc + bn + sl * 8) = val;
            }
            __syncthreads();
        }
    } else {
#pragma unroll
        for (int m = 0; m < 8; ++m)
#pragma unroll
            for (int n = 0; n < 4; ++n)
#pragma unroll
                for (int r = 0; r < 4; ++r) {
                    const int row = bm + mbase + m * 16 + lg * 4 + r;
                    const int col = bn + nbase + n * 16 + lr;
                    ((float*)Cp)[(size_t)row * ldc + col] = acc[m][n][r];
                }
    }
}

__global__ __launch_bounds__(512, 2)
void gemm256_dual(const u16* __restrict__ A1, const u16* __restrict__ B1,
                  void* __restrict__ C1, int N1, int K1, int ldc1, int nx1,
                  const u16* __restrict__ A2, const u16* __restrict__ B2,
                  void* __restrict__ C2, int N2, int K2, int ldc2, int nx2,
                  int nqk)
{
    __shared__ __align__(16) u16 lds[65536];
    const int flat = blockIdx.x;
    if (flat < nqk) {
        gemm256_body<1>(A1, B1, C1, N1, K1, ldc1, flat % nx1, flat / nx1, lds);
    } else {
        const int local = flat - nqk;
        gemm256_body<1>(A2, B2, C2, N2, K2, ldc2, local % nx2, local / nx2, lds);
    }
}

template<int OUTB>
__global__ __launch_bounds__(512, 2)
void gemm256(const u16* __restrict__ A, const u16* __restrict__ B,
             void* __restrict__ Cp, int N, int K, int ldc)
{
    __shared__ __align__(16) u16 lds[65536];
    gemm256_body<OUTB>(A, B, Cp, N, K, ldc, blockIdx.x, blockIdx.y, lds);
}

// ---------------------------------------------------------------------------
// MFMA attention with T14 async-STAGE split (k and V reg-staged; see header).
// ---------------------------------------------------------------------------
__global__ __launch_bounds__(512)
void attn_mfma(const u16* __restrict__ qk, const u16* __restrict__ vT,
               const u16* __restrict__ relk, u16* __restrict__ attn_out,
               int vld)
{
    __shared__ __align__(16) u16 kv_s[256 * 128];
    __shared__ __align__(16) u16 g_s[128 * 264];

    const int ln = blockIdx.x, h = blockIdx.y, bz = blockIdx.z;
    const int tid = threadIdx.x;
    const int w = tid >> 6, l = tid & 63;
    const int lr = l & 15, lg = l >> 4;
    const size_t qbase = (size_t)bz * BSTR_;
    const size_t qrow0 = qbase + (size_t)(ln + 1) * 128;

    // ---- Q fragments (registers) -- issued first
    bf16x8 qa[4];
    {
        const u16* qp = qk + (qrow0 + w * 16 + lr) * QKW_ + h * HD_ + lg * 8;
#pragma unroll
        for (int kk = 0; kk < 4; ++kk) qa[kk] = *(const bf16x8*)(qp + kk * 32);
    }
    asm volatile("" ::: "memory");   // pin: qa before relk gloads

    // ---- stage relk via gload_lds (pre-swizzled source, linear dest)
#pragma unroll
    for (int it = 0; it < 8; ++it) {
        const int p = it * 512 + tid;
        const int row = p >> 4;
        const int s_log = (p & 15) ^ (row & 15);
        gload_lds16(relk + (size_t)row * H_ + h * HD_ + s_log * 8, kv_s + p * 8);
    }
    asm volatile("" ::: "memory");   // pin: relk gloads before kreg loads

    // ---- issue k_ctx loads to registers (LINEAR source; write swizzled later)
    int4 kvreg[8];
#pragma unroll
    for (int it = 0; it < 8; ++it) {
        const int p = it * 512 + tid;
        const int row = p >> 4;
        const int sl = p & 15;
        kvreg[it] = *(const int4*)(qk + (qbase + (size_t)(ln * 128 + 1 + row)) * QKW_
                                   + 1536 + h * HD_ + sl * 8);
    }

    // drain qa(4) + relk(8), leave kreg(8) in flight
    asm volatile("s_waitcnt vmcnt(8)" ::: "memory");
    __builtin_amdgcn_s_barrier();

    // ---- bd MFMA (reads relk from kv_s)
    f32x4 sacc[16];
#pragma unroll
    for (int n = 0; n < 16; ++n) sacc[n] = (f32x4){0.f, 0.f, 0.f, 0.f};
#pragma unroll
    for (int n = 0; n < 16; ++n)
#pragma unroll
        for (int kk = 0; kk < 4; ++kk) {
            int row = n * 16 + lr;
            int sl = kk * 4 + lg;
            bf16x8 bfrag = *(const bf16x8*)&kv_s[row * 128 + ((sl ^ (row & 15)) << 3)];
            sacc[n] = __builtin_amdgcn_mfma_f32_16x16x32_bf16(qa[kk], bfrag, sacc[n], 0, 0, 0);
        }

    const int c = w * 16 + lg * 4;
#pragma unroll
    for (int n = 0; n < 16; ++n)
#pragma unroll
        for (int r = 0; r < 4; ++r)
            g_s[(c + r) * 264 + n * 16 + lr] = f2bf(sacc[n][r]);
    __syncthreads();   // g_s visible; all waves' relk reads of kv_s done

    // ---- write k to kv_s (compiler waits kvreg automatically)
#pragma unroll
    for (int it = 0; it < 8; ++it) {
        const int p = it * 512 + tid;
        const int row = p >> 4;
        const int sl = p & 15;
        *(int4*)&kv_s[row * 128 + (((sl ^ (row & 15)) << 3))] = kvreg[it];
    }

    // ---- issue V^T loads to registers (reuse kvreg)
#pragma unroll
    for (int it = 0; it < 8; ++it) {
        const int p = it * 512 + tid;
        const int d = p >> 5;
        const int sl = p & 31;
        kvreg[it] = *(const int4*)(vT + (size_t)(h * HD_ + d) * vld
                                   + qbase + ln * 128 + 1 + sl * 8);
    }

    // k ds_writes visible to all; vreg loads stay in flight (no vmcnt drain)
    asm volatile("s_waitcnt lgkmcnt(0)" ::: "memory");
    __builtin_amdgcn_s_barrier();

    // ---- ac MFMA
#pragma unroll
    for (int n = 0; n < 16; ++n) sacc[n] = (f32x4){0.f, 0.f, 0.f, 0.f};
#pragma unroll
    for (int n = 0; n < 16; ++n)
#pragma unroll
        for (int kk = 0; kk < 4; ++kk) {
            int row = n * 16 + lr;
            int sl = kk * 4 + lg;
            bf16x8 bfrag = *(const bf16x8*)&kv_s[row * 128 + ((sl ^ (row & 15)) << 3)];
            sacc[n] = __builtin_amdgcn_mfma_f32_16x16x32_bf16(qa[kk], bfrag, sacc[n], 0, 0, 0);
        }

    // ---- combine with shifted G + softcap (x==255 -> -1e30)
#pragma unroll
    for (int n = 0; n < 16; ++n)
#pragma unroll
        for (int r = 0; r < 4; ++r) {
            int cc = c + r;
            int x = n * 16 + lr;
            float val;
            if (x == 255) {
                val = -1e30f;
            } else {
                int dx = x - cc;
                u16 bdu = (dx >= 0) ? g_s[cc * 264 + dx]
                                    : g_s[(cc - 1) * 264 + dx + 256];
                float t = (sacc[n][r] + bf2f(bdu)) * (1.f / 50.f);
                val = 50.f * fast_tanh(t);
            }
            sacc[n][r] = val;
        }

    // ---- softmax (16-lane groups) -- vreg loads landing underneath
#pragma unroll
    for (int r = 0; r < 4; ++r) {
        float m = -1e30f;
#pragma unroll
        for (int n = 0; n < 16; ++n) m = fmaxf(m, sacc[n][r]);
#pragma unroll
        for (int off = 1; off < 16; off <<= 1) m = fmaxf(m, __shfl_xor(m, off, 16));
        float s = 0.f;
#pragma unroll
        for (int n = 0; n < 16; ++n) {
            float e = __expf(sacc[n][r] - m);
            sacc[n][r] = e;
            s += e;
        }
#pragma unroll
        for (int off = 1; off < 16; off <<= 1) s += __shfl_xor(s, off, 16);
        float inv = 1.f / s;
#pragma unroll
        for (int n = 0; n < 16; ++n) sacc[n][r] *= inv;
    }
    __syncthreads();   // all G reads + k kv_s reads complete

    // ---- write P
#pragma unroll
    for (int n = 0; n < 16; ++n)
#pragma unroll
        for (int r = 0; r < 4; ++r)
            g_s[(c + r) * 264 + n * 16 + lr] = f2bf(sacc[n][r]);

    // ---- write V^T to kv_s (compiler waits vreg automatically)
#pragma unroll
    for (int it = 0; it < 8; ++it) {
        const int p = it * 512 + tid;
        const int d = p >> 5;
        const int sl = p & 31;
        *(int4*)&kv_s[d * 256 + (((sl ^ (d & 15)) << 3))] = kvreg[it];
    }
    asm volatile("s_waitcnt lgkmcnt(0)" ::: "memory");
    __builtin_amdgcn_s_barrier();   // P + V^T visible

    // ---- PV MFMA
    f32x4 oacc[8];
#pragma unroll
    for (int n = 0; n < 8; ++n) oacc[n] = (f32x4){0.f, 0.f, 0.f, 0.f};
#pragma unroll
    for (int kk = 0; kk < 8; ++kk) {
        int prow = w * 16 + lr;
        bf16x8 pa = *(const bf16x8*)&g_s[prow * 264 + kk * 32 + lg * 8];
#pragma unroll
        for (int n = 0; n < 8; ++n) {
            int d = n * 16 + lr;
            int sl = kk * 4 + lg;
            bf16x8 vb = *(const bf16x8*)&kv_s[d * 256 + ((sl ^ (d & 15)) << 3)];
            oacc[n] = __builtin_amdgcn_mfma_f32_16x16x32_bf16(pa, vb, oacc[n], 0, 0, 0);
        }
    }

    // ---- coalesced output via LDS staging
    __syncthreads();
#pragma unroll
    for (int n = 0; n < 8; ++n)
#pragma unroll
        for (int r = 0; r < 4; ++r)
            kv_s[(c + r) * 136 + n * 16 + lr] = f2bf(oacc[n][r]);
    __syncthreads();
#pragma unroll
    for (int it = 0; it < 4; ++it) {
        const int sid = it * 512 + tid;
        const int row = sid >> 4, sl = sid & 15;
        int4 val = *(const int4*)&kv_s[row * 136 + sl * 8];
        *(int4*)(attn_out + ((size_t)bz * S_ + (size_t)(ln * 128 + row)) * H_ + h * HD_ + sl * 8) = val;
    }
}

// ---------------------------------------------------------------------------
extern "C" void kernel_launch(void* const* d_in, const int* in_sizes, int n_in,
                              void* d_out, int out_size, void* d_ws, size_t ws_size,
                              hipStream_t stream)
{
    (void)in_sizes; (void)n_in; (void)out_size;

    const float* hs    = (const float*)d_in[0];
    const float* pos   = (const float*)d_in[1];
    const float* Wq    = (const float*)d_in[2];
    const float* Wk    = (const float*)d_in[3];
    const float* Wv    = (const float*)d_in[4];
    const float* Wrel  = (const float*)d_in[5];
    const float* Wpost = (const float*)d_in[6];
    const float* pds   = (const float*)d_in[7];
    float* out = (float*)d_out;

    const long long WW = (long long)H_ * H_;
    const long long POSN = 256LL * H_;
    const long long fixed_elems = 5 * WW + 2 * POSN;

    int NB = 0;
    const int cand[3] = {4, 2, 1};
    for (int ci = 0; ci < 3; ++ci) {
        const int nb = cand[ci];
        const long long R = (long long)nb * BSTR_;
        const long long seg = R * (H_ + QKW_ + H_) + (long long)nb * S_ * H_;
        if ((fixed_elems + seg) * 2 <= (long long)ws_size) { NB = nb; break; }
    }
    if (NB == 0) return;

    const long long R = (long long)NB * BSTR_;
    const int vld = (int)R;

    u16* wqkb   = (u16*)d_ws;
    u16* wvb    = wqkb + 2 * WW;
    u16* wpostb = wvb + WW;
    u16* wrelb  = wpostb + WW;
    u16* posb   = wrelb + WW;
    u16* relkb  = posb + POSN;
    u16* hsb    = relkb + POSN;
    u16* qkb    = hsb + R * H_;
    u16* vTb    = qkb + R * QKW_;
    u16* attb   = vTb + (long long)H_ * R;

    dim3 blk(256);
    const long long BIG = 1LL << 60;

    conv_bf16<<<dim3(WW / 1024), blk, 0, stream>>>(Wq, 0, wqkb,        WW, 0, BIG, 1, pds, H_);
    conv_bf16<<<dim3(WW / 1024), blk, 0, stream>>>(Wk, 0, wqkb + WW,   WW, 0, BIG, 2, nullptr, H_);
    conv_bf16<<<dim3(WW / 1024), blk, 0, stream>>>(Wv, 0, wvb,         WW, 0, BIG, 0, nullptr, H_);
    conv_bf16<<<dim3(WW / 1024), blk, 0, stream>>>(Wpost, 0, wpostb,   WW, 0, BIG, 0, nullptr, H_);
    conv_bf16<<<dim3(WW / 1024), blk, 0, stream>>>(Wrel, 0, wrelb,     WW, 0, BIG, 0, nullptr, H_);
    conv_bf16<<<dim3(POSN / 1024), blk, 0, stream>>>(pos, 0, posb, POSN, 0, 255LL * H_, 0, nullptr, H_);

    gemm_bt<<<dim3(H_ / 128, 2), blk, 0, stream>>>(posb, wrelb, relkb, 256, H_, H_, H_);

    const long long hn = R * H_;
    const int nx1 = QKW_ / 256;
    const int nqk = nx1 * (int)(R / 256);
    const int nx2 = (int)(R / 256);
    const int nvt = nx2 * (H_ / 256);

    for (int s = 0; s < B_ / NB; ++s) {
        const long long row0 = (long long)s * NB * S_;

        conv_hs<<<dim3((unsigned)(hn / 1024)), blk, 0, stream>>>(hs, row0, hsb, hn);

        gemm256_dual<<<dim3((unsigned)(nqk + nvt)), dim3(512), 0, stream>>>(
            hsb, wqkb, qkb, QKW_, H_, QKW_, nx1,
            wvb, hsb, vTb, (int)R, H_, vld, nx2,
            nqk);

        attn_mfma<<<dim3(NB_CH, NH_, NB), dim3(512), 0, stream>>>(
            qkb, vTb, relkb, attb, vld);

        gemm256<0><<<dim3(H_ / 256, (unsigned)((long long)NB * S_ / 256)), dim3(512), 0, stream>>>(
            attb, wpostb, out + row0 * H_, H_, H_, H_);
    }
}

// Round 19
// 539.525 us; speedup vs baseline: 1.1033x; 1.1033x over previous
//
#include <hip/hip_runtime.h>
#include <hip/hip_bf16.h>
#include <math.h>

// ---------------------------------------------------------------------------
// Gemma audio layer, round 18: revert r17 reg-staging (T14 misapplied: costs
// ~16% vs gload_lds DMA). Attention keeps gload_lds but overlaps stages via
// TWO LDS buffers (67.6KB each, 135KB total):
//   A: qa | relk gload->bufB | k gload->bufA ; vmcnt(8) [relk done, k flying]
//      barrier ; bd (reads bufB)
//   B: vmcnt(0) [k landed] ; barrier [relk reads done] ; G->bufB ;
//      lgkmcnt(0) barrier
//   C: ac (reads bufA) ; barrier [k reads done] ; V gload->bufA [flies under
//      combine+softmax] ; combine+softmax ; barrier [G reads done] ; P->bufB ;
//      vmcnt(0) lgkmcnt(0) barrier [P visible, V landed]
//   D: PV (P bufB x V bufA) ; out via bufA staging.
// GEMMs (dual 256^2 stage-3-ahead + post + relk 128^2), conv unchanged from
// round 16 (541 us PASS).
// ---------------------------------------------------------------------------

#define NH_    12
#define HD_    128
#define H_     1536
#define B_     4
#define S_     4096
#define CHUNK_ 128
#define CTX_   255
#define NB_CH  32
#define QKW_   3072
#define BSTR_  4352        // 128 halo + 4096 tokens + 128 tail = 17*256

typedef unsigned short u16;
typedef short bf16x8 __attribute__((ext_vector_type(8)));
typedef float f32x4 __attribute__((ext_vector_type(4)));

static constexpr float Q_SCALE_F = (float)(0.08838834764831845 / 0.6931471805599453);
static constexpr float K_SCALE_F = (float)(1.3132616875182228 / 0.6931471805599453);

__device__ __forceinline__ u16 f2bf(float f) {
    __hip_bfloat16 h = __float2bfloat16(f);
    return __builtin_bit_cast(u16, h);
}
__device__ __forceinline__ float bf2f(u16 u) {
    unsigned int t = ((unsigned int)u) << 16;
    return __builtin_bit_cast(float, t);
}
__device__ __forceinline__ float fast_tanh(float t) {
    float u = __expf(-2.f * fabsf(t));
    float r = (1.f - u) / (1.f + u);
    return (t < 0.f) ? -r : r;
}

__device__ __forceinline__ void gload_lds16(const u16* src_global, u16* dst_lds) {
    __builtin_amdgcn_global_load_lds(
        (const __attribute__((address_space(1))) unsigned int*)src_global,
        (__attribute__((address_space(3))) unsigned int*)dst_lds,
        16, 0, 0);
}

// ---------------------------------------------------------------------------
// fp32 -> bf16 conversions (weights/pos; hs with per-batch halo layout).
// ---------------------------------------------------------------------------
__global__ __launch_bounds__(256)
void conv_bf16(const float* __restrict__ src, long long base,
               u16* __restrict__ dst, long long n,
               long long zero_below, long long zero_from,
               int mode, const float* __restrict__ pds, int ncols)
{
    long long i = ((long long)blockIdx.x * 256 + threadIdx.x) * 4;
    if (i >= n) return;
    float4 v = make_float4(0.f, 0.f, 0.f, 0.f);
    if (i >= zero_below && i < zero_from)
        v = *(const float4*)(src + base + i);
    float s = 1.f;
    if (mode == 1) {
        int row = (int)(i / ncols);
        float x = pds[row & 127];
        float sp = (x > 20.f) ? x : log1pf(__expf(x));
        s = Q_SCALE_F * sp;
    } else if (mode == 2) {
        s = K_SCALE_F;
    }
    ushort4 o = make_ushort4(f2bf(v.x * s), f2bf(v.y * s), f2bf(v.z * s), f2bf(v.w * s));
    *(ushort4*)(dst + i) = o;
}

__global__ __launch_bounds__(256)
void conv_hs(const float* __restrict__ src, long long src_row0,
             u16* __restrict__ dst, long long nelem)
{
    long long i = ((long long)blockIdx.x * 256 + threadIdx.x) * 4;
    if (i >= nelem) return;
    const int row = (int)(i / H_);
    const int col = (int)(i - (long long)row * H_);
    const int b = row / BSTR_;
    const int local = row - b * BSTR_;
    float4 v = make_float4(0.f, 0.f, 0.f, 0.f);
    if (local >= 128 && local < 128 + S_) {
        const long long srow = src_row0 + (long long)b * S_ + local - 128;
        v = *(const float4*)(src + srow * H_ + col);
    }
    ushort4 o = make_ushort4(f2bf(v.x), f2bf(v.y), f2bf(v.z), f2bf(v.w));
    *(ushort4*)(dst + i) = o;
}

// ---------------------------------------------------------------------------
// 128^2 GEMM (round-8 proven) -- kept for the small relk projection only.
// ---------------------------------------------------------------------------
#define STAGE(kt, bufc) do {                                                   \
    const int _ko = (kt) << 5;                                                 \
    gload_lds16(srcA[0] + _ko, lds + (bufc) * 4096 + pbase[0]);                \
    gload_lds16(srcA[1] + _ko, lds + (bufc) * 4096 + pbase[1]);                \
    gload_lds16(srcB[0] + _ko, lds + 16384 + (bufc) * 4096 + pbase[0]);        \
    gload_lds16(srcB[1] + _ko, lds + 16384 + (bufc) * 4096 + pbase[1]);        \
} while (0)

#define READF(afX, bfX, b) do {                                                \
    _Pragma("unroll")                                                          \
    for (int m = 0; m < 4; ++m)                                                \
        afX[m] = *(const bf16x8*)&lds[(b) * 4096 + (wr + m * 16 + lr) * 32 + sw8]; \
    _Pragma("unroll")                                                          \
    for (int n = 0; n < 4; ++n)                                                \
        bfX[n] = *(const bf16x8*)&lds[16384 + (b) * 4096 + (wc + n * 16 + lr) * 32 + sw8]; \
} while (0)

#define MFMA16(afX, bfX) do {                                                  \
    __builtin_amdgcn_s_setprio(1);                                             \
    _Pragma("unroll")                                                          \
    for (int m = 0; m < 4; ++m)                                                \
        _Pragma("unroll")                                                      \
        for (int n = 0; n < 4; ++n)                                            \
            acc[m][n] = __builtin_amdgcn_mfma_f32_16x16x32_bf16(afX[m], bfX[n], acc[m][n], 0, 0, 0); \
    __builtin_amdgcn_s_setprio(0);                                             \
} while (0)

#define ITER(t, b, afC, bfC, afN, bfN) do {                                    \
    if ((t) + 2 < nk) {                                                        \
        STAGE((t) + 2, ((b) + 2) & 3);                                         \
        asm volatile("s_waitcnt vmcnt(4)" ::: "memory");                       \
    } else {                                                                   \
        asm volatile("s_waitcnt vmcnt(0)" ::: "memory");                       \
    }                                                                          \
    __builtin_amdgcn_s_barrier();                                              \
    if ((t) + 1 < nk) READF(afN, bfN, ((b) + 1) & 3);                          \
    MFMA16(afC, bfC);                                                          \
} while (0)

__global__ __launch_bounds__(256)
void gemm_bt(const u16* __restrict__ A, const u16* __restrict__ B,
             u16* __restrict__ Cp, int M, int N, int K, int ldc)
{
    __shared__ __align__(16) u16 lds[32768];

    const int tid = threadIdx.x;
    const int w = tid >> 6, l = tid & 63;
    const int lr = l & 15, lg = l >> 4;
    const int bm = blockIdx.y * 128, bn = blockIdx.x * 128;
    const int wr = (w >> 1) * 64, wc = (w & 1) * 64;
    const int sw8 = (lg ^ ((lr >> 1) & 3)) * 8;

    const u16* srcA[2];
    const u16* srcB[2];
    int pbase[2];
#pragma unroll
    for (int c = 0; c < 2; ++c) {
        const int p = (w * 2 + c) * 64 + l;
        const int row = p >> 2;
        const int s_log = (p & 3) ^ ((row >> 1) & 3);
        pbase[c] = p * 8;
        srcA[c] = A + (size_t)(bm + row) * K + s_log * 8;
        srcB[c] = B + (size_t)(bn + row) * K + s_log * 8;
    }

    f32x4 acc[4][4];
#pragma unroll
    for (int m = 0; m < 4; ++m)
#pragma unroll
        for (int n = 0; n < 4; ++n) acc[m][n] = (f32x4){0.f, 0.f, 0.f, 0.f};

    const int nk = K >> 5;
    bf16x8 af0[4], bf0[4], af1[4], bf1[4];

    STAGE(0, 0);
    STAGE(1, 1);
    asm volatile("s_waitcnt vmcnt(4)" ::: "memory");
    __builtin_amdgcn_s_barrier();
    READF(af0, bf0, 0);

    for (int t0 = 0; t0 < nk; t0 += 4) {
        ITER(t0 + 0, 0, af0, bf0, af1, bf1);
        ITER(t0 + 1, 1, af1, bf1, af0, bf0);
        ITER(t0 + 2, 2, af0, bf0, af1, bf1);
        ITER(t0 + 3, 3, af1, bf1, af0, bf0);
    }

#pragma unroll
    for (int h = 0; h < 2; ++h) {
        if (wr == h * 64) {
#pragma unroll
            for (int m = 0; m < 4; ++m)
#pragma unroll
                for (int n = 0; n < 4; ++n)
#pragma unroll
                    for (int r = 0; r < 4; ++r)
                        lds[(m * 16 + lg * 4 + r) * 136 + wc + n * 16 + lr] =
                            f2bf(acc[m][n][r]);
        }
        __syncthreads();
#pragma unroll
        for (int it = 0; it < 4; ++it) {
            const int sid = it * 256 + tid;
            const int row = sid >> 4, sl = sid & 15;
            int4 val = *(const int4*)&lds[row * 136 + sl * 8];
            *(int4*)(Cp + (size_t)(bm + h * 64 + row) * ldc + bn + sl * 8) = val;
        }
        __syncthreads();
    }
}

// ---------------------------------------------------------------------------
// 256x256xBK32 GEMM body (round-16 proven: ring-4, STAGE-3-AHEAD,
// vmcnt 12/8/4/0, read(t) after barrier(t)).
// ---------------------------------------------------------------------------
#define STG2(kt, bufc) do {                                                    \
    const int _ko = (kt) << 5;                                                 \
    gload_lds16(srcA[0] + _ko, lds + (bufc) * 16384 + pbase[0]);               \
    gload_lds16(srcA[1] + _ko, lds + (bufc) * 16384 + pbase[1]);               \
    gload_lds16(srcB[0] + _ko, lds + (bufc) * 16384 + 8192 + pbase[0]);        \
    gload_lds16(srcB[1] + _ko, lds + (bufc) * 16384 + 8192 + pbase[1]);        \
} while (0)

#define IT3(t, b) do {                                                         \
    if ((t) + 3 < nk) {                                                        \
        STG2((t) + 3, ((b) + 3) & 3);                                          \
        asm volatile("s_waitcnt vmcnt(12)" ::: "memory");                      \
    } else if ((t) + 3 == nk) {                                                \
        asm volatile("s_waitcnt vmcnt(8)" ::: "memory");                       \
    } else if ((t) + 2 == nk) {                                                \
        asm volatile("s_waitcnt vmcnt(4)" ::: "memory");                       \
    } else {                                                                   \
        asm volatile("s_waitcnt vmcnt(0)" ::: "memory");                       \
    }                                                                          \
    __builtin_amdgcn_s_barrier();                                              \
    bf16x8 af[8], bfr[4];                                                      \
    _Pragma("unroll")                                                          \
    for (int m = 0; m < 8; ++m)                                                \
        af[m] = *(const bf16x8*)&lds[(b) * 16384 + (mbase + m * 16 + lr) * 32 + sw8]; \
    _Pragma("unroll")                                                          \
    for (int n = 0; n < 4; ++n)                                                \
        bfr[n] = *(const bf16x8*)&lds[(b) * 16384 + 8192 + (nbase + n * 16 + lr) * 32 + sw8]; \
    __builtin_amdgcn_s_setprio(1);                                             \
    _Pragma("unroll")                                                          \
    for (int m = 0; m < 8; ++m)                                                \
        _Pragma("unroll")                                                      \
        for (int n = 0; n < 4; ++n)                                            \
            acc[m][n] = __builtin_amdgcn_mfma_f32_16x16x32_bf16(af[m], bfr[n], acc[m][n], 0, 0, 0); \
    __builtin_amdgcn_s_setprio(0);                                             \
} while (0)

template<int OUTB>
__device__ __forceinline__
void gemm256_body(const u16* __restrict__ A, const u16* __restrict__ B,
                  void* __restrict__ Cp, int N, int K, int ldc,
                  int bx, int by, u16* lds)
{
    (void)N;
    const int tid = threadIdx.x;               // 0..511
    const int w = tid >> 6, l = tid & 63;
    const int lr = l & 15, lg = l >> 4;
    const int wrow = w >> 2, wcol = w & 3;     // 2 x 4 wave grid
    const int bm = by * 256, bn = bx * 256;
    const int mbase = wrow * 128;
    const int nbase = wcol * 64;
    const int sw8 = (lg ^ ((lr >> 1) & 3)) * 8;

    const u16* srcA[2];
    const u16* srcB[2];
    int pbase[2];
#pragma unroll
    for (int c = 0; c < 2; ++c) {
        const int p = c * 512 + tid;
        const int row = p >> 2;
        const int s_log = (p & 3) ^ ((row >> 1) & 3);
        pbase[c] = p * 8;
        srcA[c] = A + (size_t)(bm + row) * K + s_log * 8;
        srcB[c] = B + (size_t)(bn + row) * K + s_log * 8;
    }

    f32x4 acc[8][4];
#pragma unroll
    for (int m = 0; m < 8; ++m)
#pragma unroll
        for (int n = 0; n < 4; ++n) acc[m][n] = (f32x4){0.f, 0.f, 0.f, 0.f};

    const int nk = K >> 5;                     // 48 for K=1536; nk % 4 == 0
    STG2(0, 0);
    STG2(1, 1);
    STG2(2, 2);
    for (int t0 = 0; t0 < nk; t0 += 4) {
        IT3(t0 + 0, 0);
        IT3(t0 + 1, 1);
        IT3(t0 + 2, 2);
        IT3(t0 + 3, 3);
    }

    __syncthreads();

    if (OUTB) {
#pragma unroll
        for (int h = 0; h < 2; ++h) {
            if (wrow == h) {
#pragma unroll
                for (int m = 0; m < 8; ++m)
#pragma unroll
                    for (int n = 0; n < 4; ++n)
#pragma unroll
                        for (int r = 0; r < 4; ++r)
                            lds[(m * 16 + lg * 4 + r) * 264 + nbase + n * 16 + lr] =
                                f2bf(acc[m][n][r]);
            }
            __syncthreads();
#pragma unroll
            for (int it = 0; it < 8; ++it) {
                const int sid = it * 512 + tid;
                const int row = sid >> 5, sl = sid & 31;
                int4 val = *(const int4*)&lds[row * 264 + sl * 8];
                *(int4*)((u16*)Cp + (size_t)(bm + h * 128 + row) * ldc + bn + sl * 8) = val;
            }
            __syncthreads();
        }
    } else {
#pragma unroll
        for (int m = 0; m < 8; ++m)
#pragma unroll
            for (int n = 0; n < 4; ++n)
#pragma unroll
                for (int r = 0; r < 4; ++r) {
                    const int row = bm + mbase + m * 16 + lg * 4 + r;
                    const int col = bn + nbase + n * 16 + lr;
                    ((float*)Cp)[(size_t)row * ldc + col] = acc[m][n][r];
                }
    }
}

__global__ __launch_bounds__(512, 2)
void gemm256_dual(const u16* __restrict__ A1, const u16* __restrict__ B1,
                  void* __restrict__ C1, int N1, int K1, int ldc1, int nx1,
                  const u16* __restrict__ A2, const u16* __restrict__ B2,
                  void* __restrict__ C2, int N2, int K2, int ldc2, int nx2,
                  int nqk)
{
    __shared__ __align__(16) u16 lds[65536];
    const int flat = blockIdx.x;
    if (flat < nqk) {
        gemm256_body<1>(A1, B1, C1, N1, K1, ldc1, flat % nx1, flat / nx1, lds);
    } else {
        const int local = flat - nqk;
        gemm256_body<1>(A2, B2, C2, N2, K2, ldc2, local % nx2, local / nx2, lds);
    }
}

template<int OUTB>
__global__ __launch_bounds__(512, 2)
void gemm256(const u16* __restrict__ A, const u16* __restrict__ B,
             void* __restrict__ Cp, int N, int K, int ldc)
{
    __shared__ __align__(16) u16 lds[65536];
    gemm256_body<OUTB>(A, B, Cp, N, K, ldc, blockIdx.x, blockIdx.y, lds);
}

// ---------------------------------------------------------------------------
// MFMA attention, two-buffer overlapped gload_lds staging (see file header).
// bufB: relk -> G -> P (stride 264 for G/P, 128 for relk).
// bufA: k -> V^T -> out staging.
// ---------------------------------------------------------------------------
__global__ __launch_bounds__(512)
void attn_mfma(const u16* __restrict__ qk, const u16* __restrict__ vT,
               const u16* __restrict__ relk, u16* __restrict__ attn_out,
               int vld)
{
    __shared__ __align__(16) u16 bufA[33792];   // 67.6 KB: k -> V^T -> out
    __shared__ __align__(16) u16 bufB[33792];   // 67.6 KB: relk -> G -> P

    const int ln = blockIdx.x, h = blockIdx.y, bz = blockIdx.z;
    const int tid = threadIdx.x;
    const int w = tid >> 6, l = tid & 63;
    const int lr = l & 15, lg = l >> 4;
    const size_t qbase = (size_t)bz * BSTR_;
    const size_t qrow0 = qbase + (size_t)(ln + 1) * 128;

    // ---- Phase A: qa loads, relk -> bufB, k -> bufA (k flies under bd)
    bf16x8 qa[4];
    {
        const u16* qp = qk + (qrow0 + w * 16 + lr) * QKW_ + h * HD_ + lg * 8;
#pragma unroll
        for (int kk = 0; kk < 4; ++kk) qa[kk] = *(const bf16x8*)(qp + kk * 32);
    }
    asm volatile("" ::: "memory");   // pin: qa before relk gloads

#pragma unroll
    for (int it = 0; it < 8; ++it) {
        const int p = it * 512 + tid;
        const int row = p >> 4;
        const int s_log = (p & 15) ^ (row & 15);
        gload_lds16(relk + (size_t)row * H_ + h * HD_ + s_log * 8, bufB + p * 8);
    }
    asm volatile("" ::: "memory");   // pin: relk gloads before k gloads

#pragma unroll
    for (int it = 0; it < 8; ++it) {
        const int p = it * 512 + tid;
        const int row = p >> 4;
        const int s_log = (p & 15) ^ (row & 15);
        gload_lds16(qk + (qbase + (size_t)(ln * 128 + 1 + row)) * QKW_ + 1536 + h * HD_ + s_log * 8,
                    bufA + p * 8);
    }
    // drain qa(4)+relk(8); k(8) stays in flight
    asm volatile("s_waitcnt vmcnt(8)" ::: "memory");
    __builtin_amdgcn_s_barrier();

    // ---- bd MFMA (reads relk from bufB)
    f32x4 sacc[16];
#pragma unroll
    for (int n = 0; n < 16; ++n) sacc[n] = (f32x4){0.f, 0.f, 0.f, 0.f};
#pragma unroll
    for (int n = 0; n < 16; ++n)
#pragma unroll
        for (int kk = 0; kk < 4; ++kk) {
            int row = n * 16 + lr;
            int sl = kk * 4 + lg;
            bf16x8 bfrag = *(const bf16x8*)&bufB[row * 128 + ((sl ^ (row & 15)) << 3)];
            sacc[n] = __builtin_amdgcn_mfma_f32_16x16x32_bf16(qa[kk], bfrag, sacc[n], 0, 0, 0);
        }

    // ---- Phase B: k landed; relk reads done across waves; G -> bufB
    asm volatile("s_waitcnt vmcnt(0)" ::: "memory");
    __builtin_amdgcn_s_barrier();

    const int c = w * 16 + lg * 4;
#pragma unroll
    for (int n = 0; n < 16; ++n)
#pragma unroll
        for (int r = 0; r < 4; ++r)
            bufB[(c + r) * 264 + n * 16 + lr] = f2bf(sacc[n][r]);
    asm volatile("s_waitcnt lgkmcnt(0)" ::: "memory");
    __builtin_amdgcn_s_barrier();    // G visible to all waves

    // ---- Phase C: ac MFMA (reads k from bufA)
#pragma unroll
    for (int n = 0; n < 16; ++n) sacc[n] = (f32x4){0.f, 0.f, 0.f, 0.f};
#pragma unroll
    for (int n = 0; n < 16; ++n)
#pragma unroll
        for (int kk = 0; kk < 4; ++kk) {
            int row = n * 16 + lr;
            int sl = kk * 4 + lg;
            bf16x8 bfrag = *(const bf16x8*)&bufA[row * 128 + ((sl ^ (row & 15)) << 3)];
            sacc[n] = __builtin_amdgcn_mfma_f32_16x16x32_bf16(qa[kk], bfrag, sacc[n], 0, 0, 0);
        }

    __builtin_amdgcn_s_barrier();    // all waves' k reads of bufA complete

    // issue V^T -> bufA (flies under combine + softmax)
#pragma unroll
    for (int it = 0; it < 8; ++it) {
        const int p = it * 512 + tid;
        const int d = p >> 5;
        const int s_log = (p & 31) ^ (d & 15);
        gload_lds16(vT + (size_t)(h * HD_ + d) * vld + qbase + ln * 128 + 1 + s_log * 8,
                    bufA + p * 8);
    }

    // ---- combine with shifted G + softcap (x==255 -> -1e30)
#pragma unroll
    for (int n = 0; n < 16; ++n)
#pragma unroll
        for (int r = 0; r < 4; ++r) {
            int cc = c + r;
            int x = n * 16 + lr;
            float val;
            if (x == 255) {
                val = -1e30f;
            } else {
                int dx = x - cc;
                u16 bdu = (dx >= 0) ? bufB[cc * 264 + dx]
                                    : bufB[(cc - 1) * 264 + dx + 256];
                float t = (sacc[n][r] + bf2f(bdu)) * (1.f / 50.f);
                val = 50.f * fast_tanh(t);
            }
            sacc[n][r] = val;
        }

    // ---- softmax (16-lane groups); V DMA landing underneath
#pragma unroll
    for (int r = 0; r < 4; ++r) {
        float m = -1e30f;
#pragma unroll
        for (int n = 0; n < 16; ++n) m = fmaxf(m, sacc[n][r]);
#pragma unroll
        for (int off = 1; off < 16; off <<= 1) m = fmaxf(m, __shfl_xor(m, off, 16));
        float s = 0.f;
#pragma unroll
        for (int n = 0; n < 16; ++n) {
            float e = __expf(sacc[n][r] - m);
            sacc[n][r] = e;
            s += e;
        }
#pragma unroll
        for (int off = 1; off < 16; off <<= 1) s += __shfl_xor(s, off, 16);
        float inv = 1.f / s;
#pragma unroll
        for (int n = 0; n < 16; ++n) sacc[n][r] *= inv;
    }
    __builtin_amdgcn_s_barrier();    // all waves' G reads of bufB complete

    // ---- write P -> bufB
#pragma unroll
    for (int n = 0; n < 16; ++n)
#pragma unroll
        for (int r = 0; r < 4; ++r)
            bufB[(c + r) * 264 + n * 16 + lr] = f2bf(sacc[n][r]);
    asm volatile("s_waitcnt vmcnt(0) lgkmcnt(0)" ::: "memory");  // P written, V landed
    __builtin_amdgcn_s_barrier();

    // ---- PV MFMA (P from bufB, V from bufA)
    f32x4 oacc[8];
#pragma unroll
    for (int n = 0; n < 8; ++n) oacc[n] = (f32x4){0.f, 0.f, 0.f, 0.f};
#pragma unroll
    for (int kk = 0; kk < 8; ++kk) {
        int prow = w * 16 + lr;
        bf16x8 pa = *(const bf16x8*)&bufB[prow * 264 + kk * 32 + lg * 8];
#pragma unroll
        for (int n = 0; n < 8; ++n) {
            int d = n * 16 + lr;
            int sl = kk * 4 + lg;
            bf16x8 vb = *(const bf16x8*)&bufA[d * 256 + ((sl ^ (d & 15)) << 3)];
            oacc[n] = __builtin_amdgcn_mfma_f32_16x16x32_bf16(pa, vb, oacc[n], 0, 0, 0);
        }
    }

    // ---- coalesced output via bufA staging
    __syncthreads();
#pragma unroll
    for (int n = 0; n < 8; ++n)
#pragma unroll
        for (int r = 0; r < 4; ++r)
            bufA[(c + r) * 136 + n * 16 + lr] = f2bf(oacc[n][r]);
    __syncthreads();
#pragma unroll
    for (int it = 0; it < 4; ++it) {
        const int sid = it * 512 + tid;
        const int row = sid >> 4, sl = sid & 15;
        int4 val = *(const int4*)&bufA[row * 136 + sl * 8];
        *(int4*)(attn_out + ((size_t)bz * S_ + (size_t)(ln * 128 + row)) * H_ + h * HD_ + sl * 8) = val;
    }
}

// ---------------------------------------------------------------------------
extern "C" void kernel_launch(void* const* d_in, const int* in_sizes, int n_in,
                              void* d_out, int out_size, void* d_ws, size_t ws_size,
                              hipStream_t stream)
{
    (void)in_sizes; (void)n_in; (void)out_size;

    const float* hs    = (const float*)d_in[0];
    const float* pos   = (const float*)d_in[1];
    const float* Wq    = (const float*)d_in[2];
    const float* Wk    = (const float*)d_in[3];
    const float* Wv    = (const float*)d_in[4];
    const float* Wrel  = (const float*)d_in[5];
    const float* Wpost = (const float*)d_in[6];
    const float* pds   = (const float*)d_in[7];
    float* out = (float*)d_out;

    const long long WW = (long long)H_ * H_;
    const long long POSN = 256LL * H_;
    const long long fixed_elems = 5 * WW + 2 * POSN;

    int NB = 0;
    const int cand[3] = {4, 2, 1};
    for (int ci = 0; ci < 3; ++ci) {
        const int nb = cand[ci];
        const long long R = (long long)nb * BSTR_;
        const long long seg = R * (H_ + QKW_ + H_) + (long long)nb * S_ * H_;
        if ((fixed_elems + seg) * 2 <= (long long)ws_size) { NB = nb; break; }
    }
    if (NB == 0) return;

    const long long R = (long long)NB * BSTR_;
    const int vld = (int)R;

    u16* wqkb   = (u16*)d_ws;
    u16* wvb    = wqkb + 2 * WW;
    u16* wpostb = wvb + WW;
    u16* wrelb  = wpostb + WW;
    u16* posb   = wrelb + WW;
    u16* relkb  = posb + POSN;
    u16* hsb    = relkb + POSN;
    u16* qkb    = hsb + R * H_;
    u16* vTb    = qkb + R * QKW_;
    u16* attb   = vTb + (long long)H_ * R;

    dim3 blk(256);
    const long long BIG = 1LL << 60;

    conv_bf16<<<dim3(WW / 1024), blk, 0, stream>>>(Wq, 0, wqkb,        WW, 0, BIG, 1, pds, H_);
    conv_bf16<<<dim3(WW / 1024), blk, 0, stream>>>(Wk, 0, wqkb + WW,   WW, 0, BIG, 2, nullptr, H_);
    conv_bf16<<<dim3(WW / 1024), blk, 0, stream>>>(Wv, 0, wvb,         WW, 0, BIG, 0, nullptr, H_);
    conv_bf16<<<dim3(WW / 1024), blk, 0, stream>>>(Wpost, 0, wpostb,   WW, 0, BIG, 0, nullptr, H_);
    conv_bf16<<<dim3(WW / 1024), blk, 0, stream>>>(Wrel, 0, wrelb,     WW, 0, BIG, 0, nullptr, H_);
    conv_bf16<<<dim3(POSN / 1024), blk, 0, stream>>>(pos, 0, posb, POSN, 0, 255LL * H_, 0, nullptr, H_);

    gemm_bt<<<dim3(H_ / 128, 2), blk, 0, stream>>>(posb, wrelb, relkb, 256, H_, H_, H_);

    const long long hn = R * H_;
    const int nx1 = QKW_ / 256;
    const int nqk = nx1 * (int)(R / 256);
    const int nx2 = (int)(R / 256);
    const int nvt = nx2 * (H_ / 256);

    for (int s = 0; s < B_ / NB; ++s) {
        const long long row0 = (long long)s * NB * S_;

        conv_hs<<<dim3((unsigned)(hn / 1024)), blk, 0, stream>>>(hs, row0, hsb, hn);

        gemm256_dual<<<dim3((unsigned)(nqk + nvt)), dim3(512), 0, stream>>>(
            hsb, wqkb, qkb, QKW_, H_, QKW_, nx1,
            wvb, hsb, vTb, (int)R, H_, vld, nx2,
            nqk);

        attn_mfma<<<dim3(NB_CH, NH_, NB), dim3(512), 0, stream>>>(
            qkb, vTb, relkb, attb, vld);

        gemm256<0><<<dim3(H_ / 256, (unsigned)((long long)NB * S_ / 256)), dim3(512), 0, stream>>>(
            attb, wpostb, out + row0 * H_, H_, H_, H_);
    }
}